// Round 4
// baseline (164.511 us; speedup 1.0000x reference)
//
#include <hip/hip_runtime.h>
#include <math.h>

// ---------------------------------------------------------------------------
// LowRankLoss: rank(channel-mean(raw)) vs rank(channel-mean(rect)),
// margin-ranking loss, size-averaged.  Rank is scale/normalization-invariant,
// so we compute the rank of the channel-SUM matrix via Gaussian elimination
// with partial pivoting.
// ---------------------------------------------------------------------------

#define N_BATCH 128
#define C_CH    256
#define H_DIM   32
#define W_DIM   64
#define HW      (H_DIM * W_DIM)      // 2048 floats per channel row (8 KB)
#define HW4     (HW / 4)             // 512 float4 per channel row

// K1: channel partial sum, wave-linear streaming.
// Wave wid = plane*CPW + chunk owns CPC=256/CPW channels of one plane.
// Per iteration the wave reads ONE FULL 8KB channel row as 8 CONTIGUOUS
// 1KB dwordx4 loads (k=0..7), accumulating into 8 per-lane float4 accs
// (column hw4 = k*64+lane).  Consecutive iterations advance by 8KB, so each
// wave is a pure linear streamer (copy-kernel pattern).  No LDS, no reduce.
template <int CPW>
__global__ __launch_bounds__(512) void channel_sum_kernel(
    const float* __restrict__ raw, const float* __restrict__ rect,
    float* __restrict__ part /* [256*CPW][2048] floats */)
{
    const int CPC = C_CH / CPW;          // channels per wave
    int wid  = blockIdx.x * 8 + (threadIdx.x >> 6);
    int lane = threadIdx.x & 63;
    int plane = wid / CPW;               // 0..255  (CPW is pow2)
    int chunk = wid % CPW;
    int input = plane >> 7;
    int n     = plane & 127;

    const float4* q = (const float4*)(input ? rect : raw)
                    + ((size_t)n * C_CH + (size_t)chunk * CPC) * HW4 + lane;

    float4 a0 = make_float4(0,0,0,0), a1 = a0, a2 = a0, a3 = a0;
    float4 a4 = a0, a5 = a0, a6 = a0, a7 = a0;
#pragma unroll 1
    for (int c = 0; c < CPC; ++c) {
        const float4* r = q + (size_t)c * HW4;
        float4 x0 = r[0 * 64];
        float4 x1 = r[1 * 64];
        float4 x2 = r[2 * 64];
        float4 x3 = r[3 * 64];
        float4 x4 = r[4 * 64];
        float4 x5 = r[5 * 64];
        float4 x6 = r[6 * 64];
        float4 x7 = r[7 * 64];
        a0.x += x0.x; a0.y += x0.y; a0.z += x0.z; a0.w += x0.w;
        a1.x += x1.x; a1.y += x1.y; a1.z += x1.z; a1.w += x1.w;
        a2.x += x2.x; a2.y += x2.y; a2.z += x2.z; a2.w += x2.w;
        a3.x += x3.x; a3.y += x3.y; a3.z += x3.z; a3.w += x3.w;
        a4.x += x4.x; a4.y += x4.y; a4.z += x4.z; a4.w += x4.w;
        a5.x += x5.x; a5.y += x5.y; a5.z += x5.z; a5.w += x5.w;
        a6.x += x6.x; a6.y += x6.y; a6.z += x6.z; a6.w += x6.w;
        a7.x += x7.x; a7.y += x7.y; a7.z += x7.z; a7.w += x7.w;
    }
    float4* o = (float4*)part + (size_t)wid * HW4 + lane;
    o[0 * 64] = a0; o[1 * 64] = a1; o[2 * 64] = a2; o[3 * 64] = a3;
    o[4 * 64] = a4; o[5 * 64] = a5; o[6 * 64] = a6; o[7 * 64] = a7;
}

// K2: rank of one 32x64 matrix per single-wave block.  Sums the CPW chunk
// partials inline on load, then register-resident GE with partial pivoting;
// lane t owns column t.  All register arrays statically indexed.
template <int CPW>
__global__ __launch_bounds__(64) void rank_kernel(
    const float* __restrict__ part, float* __restrict__ ranks)
{
    int mat = blockIdx.x;               // 0..255
    int t   = threadIdx.x;              // 0..63 = column owner
    const float* base = part + (size_t)mat * CPW * HW;

    float a[H_DIM];
#pragma unroll
    for (int i = 0; i < H_DIM; ++i) {
        float s = 0.0f;
#pragma unroll
        for (int k = 0; k < CPW; ++k)
            s += base[k * HW + i * W_DIM + t];
        a[i] = s;
    }

    unsigned used = 0;                  // bitmask of consumed pivot rows
    int rank = 0;
    for (int c = 0; c < W_DIM; ++c) {
        // broadcast column c to all lanes (wave-uniform after this)
        float v[H_DIM];
#pragma unroll
        for (int i = 0; i < H_DIM; ++i) v[i] = __shfl(a[i], c);

        // pivot: argmax |v_i| over unused rows (uniform computation)
        float best = 0.0f; int p = -1;
#pragma unroll
        for (int i = 0; i < H_DIM; ++i) {
            float av = fabsf(v[i]);
            bool cand = (((used >> i) & 1u) == 0u) && (av > best);
            best = cand ? av : best;
            p    = cand ? i  : p;
        }
        if (p >= 0) {
            used |= (1u << p);
            ++rank;
            float ap = 0.0f, vp = 1.0f;
#pragma unroll
            for (int i = 0; i < H_DIM; ++i) {
                if (i == p) { ap = a[i]; vp = v[i]; }
            }
            float inv = 1.0f / vp;
#pragma unroll
            for (int i = 0; i < H_DIM; ++i) {
                if (((used >> i) & 1u) == 0u) a[i] -= (v[i] * inv) * ap;
            }
            if (rank == H_DIM) break;
        }
    }
    if (t == 0) ranks[mat] = (float)rank;
}

// K3: loss = sum_n max(0, -(rank1[n]-rank2[n])) / N   (y=1, margin=0)
__global__ __launch_bounds__(128) void loss_kernel(
    const float* __restrict__ ranks, float* __restrict__ out)
{
    __shared__ float red[128];
    int t = threadIdx.x;
    float r1 = ranks[t];              // raw
    float r2 = ranks[N_BATCH + t];    // rectified
    red[t] = fmaxf(0.0f, -(r1 - r2));
    __syncthreads();
    for (int s = 64; s > 0; s >>= 1) {
        if (t < s) red[t] += red[t + s];
        __syncthreads();
    }
    if (t == 0) out[0] = red[0] / (float)N_BATCH;
}

template <int CPW>
static void run_path(const float* raw, const float* rect, float* ws,
                     float* out, hipStream_t stream)
{
    float* part  = ws;
    float* ranks = part + (size_t)2 * N_BATCH * CPW * HW;
    // 8 waves per block -> blocks = 256*CPW/8 = 32*CPW
    channel_sum_kernel<CPW><<<32 * CPW, 512, 0, stream>>>(raw, rect, part);
    rank_kernel<CPW><<<2 * N_BATCH, 64, 0, stream>>>(part, ranks);
    loss_kernel<<<1, 128, 0, stream>>>(ranks, out);
}

extern "C" void kernel_launch(void* const* d_in, const int* in_sizes, int n_in,
                              void* d_out, int out_size, void* d_ws, size_t ws_size,
                              hipStream_t stream)
{
    const float* raw  = (const float*)d_in[0];
    const float* rect = (const float*)d_in[1];
    float* out = (float*)d_out;
    float* ws  = (float*)d_ws;

    auto need = [](int cpw) {
        return (size_t)2 * N_BATCH * cpw * HW * sizeof(float) + 4096;
    };
    if      (ws_size >= need(16)) run_path<16>(raw, rect, ws, out, stream);
    else if (ws_size >= need(8))  run_path<8>(raw, rect, ws, out, stream);
    else if (ws_size >= need(4))  run_path<4>(raw, rect, ws, out, stream);
    else                          run_path<1>(raw, rect, ws, out, stream);
}

// Round 6
// 134.121 us; speedup vs baseline: 1.2266x; 1.2266x over previous
//
#include <hip/hip_runtime.h>
#include <math.h>

// ---------------------------------------------------------------------------
// LowRankLoss: rank(channel-mean(raw)) vs rank(channel-mean(rect)),
// margin-ranking loss, size-averaged.  Rank is scale/normalization-invariant,
// so we compute the rank of the channel-SUM matrix via Gaussian elimination
// with partial pivoting.
//
// R6 = R5 retry: identical to R3 (best, 144.3us) EXCEPT K1 loads are
// nontemporal, via a native ext_vector_type(4) float pointer (the HIP
// float4 class type is rejected by __builtin_nontemporal_load).
// ---------------------------------------------------------------------------

#define N_BATCH 128
#define C_CH    256
#define H_DIM   32
#define W_DIM   64
#define HW      (H_DIM * W_DIM)      // 2048 floats per channel row
#define HW4     (HW / 4)             // 512 float4 per channel row

typedef float floatx4 __attribute__((ext_vector_type(4)));

// K1: channel partial sum.  Block b = (plane, chunk): plane = (input,n),
// chunk = one of CHUNKS groups of C/CHUNKS channels.  The block streams a
// CONTIGUOUS (C/CHUNKS)*8KB region: per iteration the 512 threads read one
// 8KB channel row; thread t owns float4 slot t (no LDS, no intra-block
// reduce).  8 named nontemporal loads per batch for memory-level parallelism.
template <int CHUNKS>
__global__ __launch_bounds__(512) void channel_sum_kernel(
    const float* __restrict__ raw, const float* __restrict__ rect,
    float* __restrict__ part /* [2*128*CHUNKS][2048] floats */)
{
    const int CPR = C_CH / CHUNKS;       // channels per block
    int b     = blockIdx.x;
    int chunk = b % CHUNKS;
    int plane = b / CHUNKS;              // 0..255
    int input = plane >> 7;
    int n     = plane & 127;

    const float* src = input ? rect : raw;
    const floatx4* p = (const floatx4*)(src +
        ((size_t)n * C_CH + (size_t)chunk * CPR) * HW) + threadIdx.x;

    floatx4 acc = (floatx4)(0.0f);
#pragma unroll 1
    for (int cb = 0; cb < CPR; cb += 8) {
        floatx4 x0 = __builtin_nontemporal_load(p + (cb + 0) * HW4);
        floatx4 x1 = __builtin_nontemporal_load(p + (cb + 1) * HW4);
        floatx4 x2 = __builtin_nontemporal_load(p + (cb + 2) * HW4);
        floatx4 x3 = __builtin_nontemporal_load(p + (cb + 3) * HW4);
        floatx4 x4 = __builtin_nontemporal_load(p + (cb + 4) * HW4);
        floatx4 x5 = __builtin_nontemporal_load(p + (cb + 5) * HW4);
        floatx4 x6 = __builtin_nontemporal_load(p + (cb + 6) * HW4);
        floatx4 x7 = __builtin_nontemporal_load(p + (cb + 7) * HW4);
        acc += ((x0 + x1) + (x2 + x3)) + ((x4 + x5) + (x6 + x7));
    }
    ((floatx4*)part)[(size_t)b * 512 + threadIdx.x] = acc;
}

// K2: rank of one 32x64 matrix per single-wave block.  Sums the CHUNKS
// partials inline on load, then register-resident GE with partial pivoting;
// lane t owns column t.  All register arrays statically indexed.
template <int CHUNKS>
__global__ __launch_bounds__(64) void rank_kernel(
    const float* __restrict__ part, float* __restrict__ ranks)
{
    int mat = blockIdx.x;               // 0..255
    int t   = threadIdx.x;              // 0..63 = column owner
    const float* base = part + (size_t)mat * CHUNKS * HW;

    float a[H_DIM];
#pragma unroll
    for (int i = 0; i < H_DIM; ++i) {
        float s = 0.0f;
#pragma unroll
        for (int k = 0; k < CHUNKS; ++k)
            s += base[k * HW + i * W_DIM + t];
        a[i] = s;
    }

    unsigned used = 0;                  // bitmask of consumed pivot rows
    int rank = 0;
    for (int c = 0; c < W_DIM; ++c) {
        // broadcast column c to all lanes (wave-uniform after this)
        float v[H_DIM];
#pragma unroll
        for (int i = 0; i < H_DIM; ++i) v[i] = __shfl(a[i], c);

        // pivot: argmax |v_i| over unused rows (uniform computation)
        float best = 0.0f; int p = -1;
#pragma unroll
        for (int i = 0; i < H_DIM; ++i) {
            float av = fabsf(v[i]);
            bool cand = (((used >> i) & 1u) == 0u) && (av > best);
            best = cand ? av : best;
            p    = cand ? i  : p;
        }
        if (p >= 0) {
            used |= (1u << p);
            ++rank;
            float ap = 0.0f, vp = 1.0f;
#pragma unroll
            for (int i = 0; i < H_DIM; ++i) {
                if (i == p) { ap = a[i]; vp = v[i]; }
            }
            float inv = 1.0f / vp;
#pragma unroll
            for (int i = 0; i < H_DIM; ++i) {
                if (((used >> i) & 1u) == 0u) a[i] -= (v[i] * inv) * ap;
            }
            if (rank == H_DIM) break;
        }
    }
    if (t == 0) ranks[mat] = (float)rank;
}

// K3: loss = sum_n max(0, -(rank1[n]-rank2[n])) / N   (y=1, margin=0)
__global__ __launch_bounds__(128) void loss_kernel(
    const float* __restrict__ ranks, float* __restrict__ out)
{
    __shared__ float red[128];
    int t = threadIdx.x;
    float r1 = ranks[t];              // raw
    float r2 = ranks[N_BATCH + t];    // rectified
    red[t] = fmaxf(0.0f, -(r1 - r2));
    __syncthreads();
    for (int s = 64; s > 0; s >>= 1) {
        if (t < s) red[t] += red[t + s];
        __syncthreads();
    }
    if (t == 0) out[0] = red[0] / (float)N_BATCH;
}

extern "C" void kernel_launch(void* const* d_in, const int* in_sizes, int n_in,
                              void* d_out, int out_size, void* d_ws, size_t ws_size,
                              hipStream_t stream)
{
    const float* raw  = (const float*)d_in[0];
    const float* rect = (const float*)d_in[1];
    float* out = (float*)d_out;
    float* part = (float*)d_ws;

    const size_t need4 = (size_t)2 * N_BATCH * 4 * HW * sizeof(float) + 1024;
    if (ws_size >= need4) {
        // 4 chunks of 64 channels: 1024 blocks, each streams 512KB contiguous
        float* ranks = part + (size_t)2 * N_BATCH * 4 * HW;
        channel_sum_kernel<4><<<2 * N_BATCH * 4, 512, 0, stream>>>(raw, rect, part);
        rank_kernel<4><<<2 * N_BATCH, 64, 0, stream>>>(part, ranks);
        loss_kernel<<<1, 128, 0, stream>>>(ranks, out);
    } else {
        // fallback: 256 blocks, each streams a full 2MB plane
        float* ranks = part + (size_t)2 * N_BATCH * HW;
        channel_sum_kernel<1><<<2 * N_BATCH, 512, 0, stream>>>(raw, rect, part);
        rank_kernel<1><<<2 * N_BATCH, 64, 0, stream>>>(part, ranks);
        loss_kernel<<<1, 128, 0, stream>>>(ranks, out);
    }
}